// Round 10
// baseline (137.210 us; speedup 1.0000x reference)
//
#include <hip/hip_runtime.h>

#define TS 1000
#define NCOL 1024u
#define NROWU 4096u
#define NUNITS (NCOL + NROWU)

__device__ __forceinline__ double wred(double v) {
#pragma unroll
    for (int o = 32; o > 0; o >>= 1) v += __shfl_down(v, o, 64);
    return v;
}

__device__ __forceinline__ void scat(unsigned* bins, float v, unsigned val) {
    if (v != 0.0f) {
        int q = (int)(v * 1000.0f) - 1;
        if (q < 0) q += TS;
        atomicMax(&bins[q], val);
    }
}

__global__ void kinit(unsigned* w, int n) {
    int i = blockIdx.x * blockDim.x + threadIdx.x;
    if (i < n) w[i] = 0u;
}

// Persistent-grid version of R9 (80.8us): 1280 blocks (5/CU x 256 CU, all
// co-resident), ticket-dispatched work units. 1024 coarse column units
// (16-col stripe, R9 col body verbatim) served FIRST, then 4096 fine row
// units (4 rows, one per wave, R9 row body verbatim) pack the tail.
// Fixes the 2048-block / 1280-slot quantization (Occ 40.6% vs 62.5% cap).
__global__ __launch_bounds__(256, 4) void kmain(const float* __restrict__ R,
                                                const float* __restrict__ T,
                                                double* __restrict__ acc,
                                                int ncopy_mask,
                                                unsigned* __restrict__ ticket) {
    __shared__ unsigned bins[8000];
    __shared__ unsigned u_sh;
    const int tid = threadIdx.x;
    const int lane = tid & 63, wv = tid >> 6;
    const uint4 z4 = make_uint4(0u, 0u, 0u, 0u);
    double* accrow = acc + (size_t)(blockIdx.x & ncopy_mask) * 16;

    {
        uint4* p = (uint4*)bins;
        for (int i = tid; i < 2000; i += 256) p[i] = z4;
    }

    float t0 = 0.f, tsum = 0.f;  int tc1 = 0;  // vt
    float ys0 = 0.f, yss = 0.f;  int yc1 = 0;  // vy
    float xs0 = 0.f, xss = 0.f;  int xc1 = 0;  // vx

    unsigned* bR = bins + wv * 2000;  // row-unit wave-private slices
    unsigned* bT = bR + 1000;
    uint4* r4w = (uint4*)bR;
    uint4* t4w = (uint4*)bT;
    uint4* r4b = (uint4*)bins;           // col-unit block-shared: [4 cols][1000] R
    uint4* t4b = (uint4*)(bins + 4000);  // [4 cols][1000] T

    for (;;) {
        if (tid == 0) u_sh = atomicAdd(ticket, 1u);
        __syncthreads();  // publish u_sh; prior unit's LDS state settled
        const unsigned u = u_sh;
        if (u >= NUNITS) break;

        if (u < NCOL) {
            // ========== column unit: 16-col stripe (R9 body) ==========
            const int b = (int)(u >> 5);
            const int line = (int)(u & 31u);
            const float* Rb = R + (size_t)b * (512 * 512) + (size_t)line * 16;
            const float* Tb = T + (size_t)b * (512 * 512) + (size_t)line * 16;

            float4 ra[8], ta[8];
#pragma unroll
            for (int k = 0; k < 8; k++) {
                const int h = k * 64 + (tid >> 2);
                const int sub = (tid + k) & 3;
                const size_t off = (size_t)h * 512 + sub * 4;
                ra[k] = *(const float4*)(Rb + off);
                ta[k] = *(const float4*)(Tb + off);
            }
#pragma unroll
            for (int p = 0; p < 4; p++) {
#pragma unroll
                for (int k = 0; k < 8; k++) {
                    if (((tid + k) & 3) == p) {
                        const unsigned h = (unsigned)(k * 64 + (tid >> 2));
                        scat(bins + 0 * 1000, ra[k].x, h);
                        scat(bins + 1 * 1000, ra[k].y, h);
                        scat(bins + 2 * 1000, ra[k].z, h);
                        scat(bins + 3 * 1000, ra[k].w, h);
                        scat(bins + 4000 + 0 * 1000, ta[k].x, h);
                        scat(bins + 4000 + 1 * 1000, ta[k].y, h);
                        scat(bins + 4000 + 2 * 1000, ta[k].z, h);
                        scat(bins + 4000 + 3 * 1000, ta[k].w, h);
                    }
                }
                __syncthreads();  // scatters visible
                for (int g = tid; g < 1000; g += 256) {
                    uint4 rg = r4b[g], tg = t4b[g];
                    if (rg.x | rg.y | rg.z | rg.w | tg.x | tg.y | tg.z | tg.w) {
                        r4b[g] = z4;
                        t4b[g] = z4;
                        unsigned ru[4] = {rg.x, rg.y, rg.z, rg.w};
                        unsigned tu[4] = {tg.x, tg.y, tg.z, tg.w};
#pragma unroll
                        for (int j = 0; j < 4; j++) {
                            float rb = (float)ru[j], tb = (float)tu[j];
                            float d = rb - tb, d2 = d * d;
                            bool tz = (tb == 0.0f);
                            xss += d2;
                            xs0 += tz ? d2 : 0.0f;
                            xc1 += tz ? 0 : 1;
                        }
                    }
                }
                if (p < 3) __syncthreads();  // re-clears visible before next phase
            }
        } else {
            // ========== row unit: 4 rows, one per wave (R9 body) ==========
            const size_t row = (size_t)(u - NCOL) * 4 + (size_t)wv;
            const float4* R4 = (const float4*)(R + row * 512);
            const float4* T4 = (const float4*)(T + row * 512);
#pragma unroll
            for (int k = 0; k < 2; k++) {
                const int c = lane + k * 64;  // float4 index within row
                float4 rv = R4[c];
                float4 tv = T4[c];
                float rr[4] = {rv.x, rv.y, rv.z, rv.w};
                float tt[4] = {tv.x, tv.y, tv.z, tv.w};
#pragma unroll
                for (int j = 0; j < 4; j++) {
                    float a = rr[j], b = tt[j];
                    float d = a - b, d2 = d * d;
                    bool bz = (b == 0.0f);
                    tsum += d2;
                    t0 += bz ? d2 : 0.0f;
                    tc1 += bz ? 0 : 1;
                    scat(bR, a, (unsigned)(c * 4 + j));
                    scat(bT, b, (unsigned)(c * 4 + j));
                }
            }
            // no internal barrier: wave-private slice, same-wave DS ordering
            // (validated R6: absmax 0.0 with this exact pattern)
            for (int g = lane; g < 250; g += 64) {
                uint4 rg = r4w[g], tg = t4w[g];
                if (rg.x | rg.y | rg.z | rg.w | tg.x | tg.y | tg.z | tg.w) {
                    r4w[g] = z4;
                    t4w[g] = z4;
                    unsigned ru[4] = {rg.x, rg.y, rg.z, rg.w};
                    unsigned tu[4] = {tg.x, tg.y, tg.z, tg.w};
#pragma unroll
                    for (int j2 = 0; j2 < 4; j2++) {
                        float rb = (float)ru[j2], tb = (float)tu[j2];
                        float d = rb - tb, d2 = d * d;
                        bool tz = (tb == 0.0f);
                        yss += d2;
                        ys0 += tz ? d2 : 0.0f;
                        yc1 += tz ? 0 : 1;
                    }
                }
            }
        }
        __syncthreads();  // all threads consumed u_sh; bins clean for next unit
    }

    double v0 = wred((double)t0), v1 = wred((double)tsum), v2 = wred((double)tc1);
    double v3 = wred((double)ys0), v4 = wred((double)yss), v5 = wred((double)yc1);
    double v6 = wred((double)xs0), v7 = wred((double)xss), v8 = wred((double)xc1);
    if (lane == 0) {
        atomicAdd(&accrow[0], v0);
        atomicAdd(&accrow[1], v1);
        atomicAdd(&accrow[2], v2);
        atomicAdd(&accrow[3], v3);
        atomicAdd(&accrow[4], v4);
        atomicAdd(&accrow[5], v5);
        atomicAdd(&accrow[6], v6);
        atomicAdd(&accrow[7], v7);
        atomicAdd(&accrow[8], v8);
    }
}

__global__ void kfin(const double* __restrict__ acc, float* __restrict__ out,
                     int ncopy) {
    const int lane = threadIdx.x;  // 64 threads
    double v[9];
#pragma unroll
    for (int k = 0; k < 9; k++) v[k] = 0.0;
    if (lane < ncopy) {
#pragma unroll
        for (int k = 0; k < 9; k++) v[k] = acc[(size_t)lane * 16 + k];
    }
#pragma unroll
    for (int k = 0; k < 9; k++) {
#pragma unroll
        for (int o = 16; o > 0; o >>= 1) v[k] += __shfl_down(v[k], o, 64);
    }
    if (lane == 0) {
        const double NT = 8388608.0;   // 32*512*512
        const double NB = 16384000.0;  // 32*512*1000
        double vt_c1 = v[2], vy_c1 = v[5], vx_c1 = v[8];
        double vt_c0 = NT - vt_c1, vy_c0 = NB - vy_c1, vx_c0 = NB - vx_c1;
        double vt_s1 = v[1] - v[0];
        double vy_s1 = v[4] - v[3];
        double vx_s1 = v[7] - v[6];
        double vt = (vt_c0 > 0.0 ? v[0] / vt_c0 : 0.0) +
                    (vt_c1 > 0.0 ? vt_s1 / vt_c1 : 0.0);
        double vy = (vy_c0 > 0.0 ? v[3] / vy_c0 : 0.0) +
                    (vy_c1 > 0.0 ? vy_s1 / vy_c1 : 0.0);
        double vx = (vx_c0 > 0.0 ? v[6] / vx_c0 : 0.0) +
                    (vx_c1 > 0.0 ? vx_s1 / vx_c1 : 0.0);
        out[0] = (float)(vt + vx + vy);
    }
}

extern "C" void kernel_launch(void* const* d_in, const int* in_sizes, int n_in,
                              void* d_out, int out_size, void* d_ws, size_t ws_size,
                              hipStream_t stream) {
    const float* R = (const float*)d_in[0];  // reconstructed_image
    const float* T = (const float*)d_in[1];  // target_image
    double* acc = (double*)d_ws;
    float* out = (float*)d_out;

    // power-of-two accumulator copies (16 doubles = 128B each) + ticket word
    int ncopy = 16;
    while (ncopy > 1 &&
           (size_t)ncopy * 16 * sizeof(double) + sizeof(unsigned) > ws_size)
        ncopy >>= 1;
    unsigned* ticket = (unsigned*)(acc + (size_t)ncopy * 16);

    hipLaunchKernelGGL(kinit, dim3(4), dim3(256), 0, stream,
                       (unsigned*)d_ws, ncopy * 32 + 1);
    hipLaunchKernelGGL(kmain, dim3(1280), dim3(256), 0, stream, R, T, acc,
                       ncopy - 1, ticket);
    hipLaunchKernelGGL(kfin, dim3(1), dim3(64), 0, stream, acc, out, ncopy);
}